// Round 7
// baseline (233.880 us; speedup 1.0000x reference)
//
#include <hip/hip_runtime.h>
#include <math.h>

#define BUF_SIZE 1000
// Mirror the reference's constants exactly (LN2 truncated to 0.693147).
#define TARGET_LOG_MEAN 7.6438561897747395f            // float(np.log2(200.0))
#define TARGET_LOG_STD  (40.0f / (200.0f * 0.693147f)) // 0.288538...

// ---------------------------------------------------------------------------
// Round 7. Two-kernel structure (best measured: 224.8/225.1 total).
// ONE change vs round 6: apply kernel processes 2 independent float4 per
// thread, both loads issued back-to-back before any use (double per-thread
// MLP, half the blocks, still one-shot / no loop-carried state).
// Cross-round arithmetic: fixed harness = 151 us; one-shot 1xfloat4 apply
// = ~68 us = 3.9 TB/s logical vs 6.29 TB/s copy ceiling (m13) => latency/
// issue-limited, not BW-limited. No nontemporal builtins (3/3 container
// failures correlate: rounds 1,2,5).
// ---------------------------------------------------------------------------

// Kernel 1: stats of the last min(1000, n_valid) valid log2-pitches.
// Single block, 256 threads, backward scan in 2048-element chunks.
// (unchanged from round 6 — measured ~3-4 us serial)
__global__ __launch_bounds__(256) void stats_kernel(
    const float* __restrict__ pitch, long long n, float* __restrict__ stats) {
    const int tid  = threadIdx.x;
    const int lane = tid & 63;
    const int wid  = tid >> 6;          // 0..3 (4 waves)

    __shared__ int    s_wtot[4];
    __shared__ double s_red[8];

    const float4* __restrict__ in4 = (const float4*)pitch;

    double sum = 0.0, sumsq = 0.0;
    long long count_so_far = 0;

    // bits for lanes strictly above mine (within my wave)
    const unsigned long long above =
        (lane == 63) ? 0ULL : (~0ULL << (lane + 1));

    const long long nchunks = (n + 2047) >> 11;   // 2048-element chunks
    for (long long c = nchunks - 1; c >= 0; --c) {
        const long long base = (c << 11) + (long long)tid * 8;
        float v[8];
        if (base + 8 <= n) {
            // base is a multiple of 8 -> float4-aligned
            const float4 x = in4[(base >> 2)];
            const float4 y = in4[(base >> 2) + 1];
            v[0] = x.x; v[1] = x.y; v[2] = x.z; v[3] = x.w;
            v[4] = y.x; v[5] = y.y; v[6] = y.z; v[7] = y.w;
        } else {
#pragma unroll
            for (int j = 0; j < 8; ++j) {
                const long long idx = base + j;
                v[j] = (idx < n) ? pitch[idx] : 0.0f;
            }
        }

        int valid[8];
        int suff_wave = 0;   // valid elems in higher lanes of my wave
        int wtot = 0;        // valid elems in my wave (wave-uniform)
#pragma unroll
        for (int j = 0; j < 8; ++j) {
            valid[j] = (v[j] > 0.0f) ? 1 : 0;
            const unsigned long long m = __ballot(valid[j]);
            suff_wave += __popcll(m & above);
            wtot      += __popcll(m);
        }
        if (lane == 0) s_wtot[wid] = wtot;
        __syncthreads();
        int suff_after = suff_wave;      // + valid elems in higher waves
        int total = 0;
#pragma unroll
        for (int w = 0; w < 4; ++w) {
            const int t = s_wtot[w];
            total += t;
            if (w > wid) suff_after += t;
        }

        // Walk my 8 elements newest-to-oldest, assigning global reverse ranks.
        int r = 0;
#pragma unroll
        for (int j = 7; j >= 0; --j) {
            if (valid[j]) {
                const long long rev = count_so_far + suff_after + r;
                if (rev < BUF_SIZE) {
                    const double lp = (double)__log2f(v[j]);
                    sum   += lp;
                    sumsq += lp * lp;
                }
                r++;
            }
        }
        count_so_far += total;
        __syncthreads();                 // s_wtot reused next iteration
        if (count_so_far >= BUF_SIZE) break;   // uniform across block
    }

    // Wave-level double reduction, then 4-way LDS combine.
#pragma unroll
    for (int off = 32; off > 0; off >>= 1) {
        sum   += __shfl_down(sum,   off, 64);
        sumsq += __shfl_down(sumsq, off, 64);
    }
    if (lane == 0) { s_red[wid] = sum; s_red[4 + wid] = sumsq; }
    __syncthreads();
    if (tid == 0) {
        const double tsum   = s_red[0] + s_red[1] + s_red[2] + s_red[3];
        const double tsumsq = s_red[4] + s_red[5] + s_red[6] + s_red[7];
        const long long count =
            (count_so_far < BUF_SIZE) ? count_so_far : BUF_SIZE;
        float mean, stdv;
        if (count == 0) {
            mean = 0.0f;
            stdv = 1.0f;
        } else {
            mean = (float)(tsum / (double)count);
            if (count > 1) {
                double var = (tsumsq - tsum * tsum / (double)count) /
                             (double)(count - 1);
                if (var < 0.0) var = 0.0;
                stdv = (float)sqrt(var);
            } else {
                stdv = 1.0f;
            }
        }
        if (stdv < 1e-7f) stdv = 1e-7f;
        const float scale = TARGET_LOG_STD / stdv;
        stats[0] = scale;
        stats[1] = TARGET_LOG_MEAN - mean * scale;
    }
}

// Kernel 2: streaming elementwise transform. One-shot blocks, TWO float4
// per thread, both loads issued before any use (back-to-back vmem issue,
// 2 outstanding 16B loads/thread). Loop retained only as a safety net for
// sizes where grid*2 < n4.
__global__ __launch_bounds__(256) void apply_kernel(
    const float4* __restrict__ in4, float4* __restrict__ out4, long long n4,
    const float* __restrict__ pitch, float* __restrict__ out, long long n,
    const float* __restrict__ stats) {
    const float scale = stats[0];
    const float bias  = stats[1];
    const long long T   = (long long)gridDim.x * blockDim.x;  // total threads
    const long long gid = (long long)blockIdx.x * blockDim.x + threadIdx.x;

    for (long long k = gid; k < n4; k += 2 * T) {
        const long long k2 = k + T;
        // Issue both loads before any use.
        const float4 p0 = in4[k];
        float4 p1;
        const bool has2 = (k2 < n4);
        if (has2) p1 = in4[k2];

        float4 o0;
        o0.x = (p0.x > 0.0f) ? exp2f(fmaf(__log2f(p0.x), scale, bias)) : 0.0f;
        o0.y = (p0.y > 0.0f) ? exp2f(fmaf(__log2f(p0.y), scale, bias)) : 0.0f;
        o0.z = (p0.z > 0.0f) ? exp2f(fmaf(__log2f(p0.z), scale, bias)) : 0.0f;
        o0.w = (p0.w > 0.0f) ? exp2f(fmaf(__log2f(p0.w), scale, bias)) : 0.0f;
        out4[k] = o0;

        if (has2) {
            float4 o1;
            o1.x = (p1.x > 0.0f) ? exp2f(fmaf(__log2f(p1.x), scale, bias)) : 0.0f;
            o1.y = (p1.y > 0.0f) ? exp2f(fmaf(__log2f(p1.y), scale, bias)) : 0.0f;
            o1.z = (p1.z > 0.0f) ? exp2f(fmaf(__log2f(p1.z), scale, bias)) : 0.0f;
            o1.w = (p1.w > 0.0f) ? exp2f(fmaf(__log2f(p1.w), scale, bias)) : 0.0f;
            out4[k2] = o1;
        }
    }

    // Scalar tail (n not divisible by 4; dead for n = 2^25).
    const long long tail_start = n4 * 4;
    for (long long k = tail_start + gid; k < n; k += T) {
        const float p = pitch[k];
        out[k] = (p > 0.0f) ? exp2f(fmaf(__log2f(p), scale, bias)) : 0.0f;
    }
}

extern "C" void kernel_launch(void* const* d_in, const int* in_sizes, int n_in,
                              void* d_out, int out_size, void* d_ws, size_t ws_size,
                              hipStream_t stream) {
    const float* pitch = (const float*)d_in[0];
    float* out = (float*)d_out;
    const long long n = (long long)in_sizes[0];
    float* stats = (float*)d_ws;   // [0]=scale, [1]=bias

    stats_kernel<<<1, 256, 0, stream>>>(pitch, n, stats);

    // One-shot: each thread handles exactly 2 float4 (n4 = 2^23 ->
    // 16384 blocks x 256 threads x 2).
    const long long n4 = n / 4;
    long long want = (n4 + 511) / 512;          // threads cover n4/2 each... 2/thread
    int blocks = (int)((want < 32768) ? want : 32768);
    if (blocks < 1) blocks = 1;
    apply_kernel<<<blocks, 256, 0, stream>>>((const float4*)pitch, (float4*)out,
                                             n4, pitch, out, n, stats);
}

// Round 8
// 223.925 us; speedup vs baseline: 1.0445x; 1.0445x over previous
//
#include <hip/hip_runtime.h>
#include <math.h>
#include <stdint.h>

#define BUF_SIZE 1000
// Mirror the reference's constants exactly (LN2 truncated to 0.693147).
#define TARGET_LOG_MEAN 7.6438561897747395f            // float(np.log2(200.0))
#define TARGET_LOG_STD  (40.0f / (200.0f * 0.693147f)) // 0.288538...

// Native clang vector type for clean "v"-constraint asm operands.
typedef float fvec4 __attribute__((ext_vector_type(4)));

// Nontemporal 16B store via inline asm (`nt` flag = no cache retention).
// NOTE: __builtin_nontemporal_store is banned in this session (3/3 container
// failures correlate with the builtin: rounds 1,2,5). Inline asm is a
// different compiler path. Fire-and-forget: no waitcnt, same as compiler-
// emitted plain stores; end-of-dispatch release covers visibility.
__device__ __forceinline__ void nt_store_f4(float4* addr, const float4& v) {
    fvec4 x;
    x[0] = v.x; x[1] = v.y; x[2] = v.z; x[3] = v.w;
    asm volatile("global_store_dwordx4 %0, %1, off nt"
                 :: "v"(addr), "v"(x) : "memory");
}

// ---------------------------------------------------------------------------
// Round 8. Round-6 source (tied-best, 225.1) with ONE change: apply's store
// is nontemporal. Theory: the 134 MB zero-reuse write stream write-allocates
// in L2/L3, evicting input lines (R7 counters: FETCH=67MB of a 134MB input =
// 50% L3 read-hit that we want to KEEP; WRITE=134MB all-HBM either way).
// nt stores stop the write stream from thrashing the read stream's cache.
// Loads stay cached on purpose.
// ---------------------------------------------------------------------------

// Kernel 1: stats of the last min(1000, n_valid) valid log2-pitches.
// Single block, 256 threads, backward scan in 2048-element chunks.
// (unchanged from round 6 — ~3-4 us serial)
__global__ __launch_bounds__(256) void stats_kernel(
    const float* __restrict__ pitch, long long n, float* __restrict__ stats) {
    const int tid  = threadIdx.x;
    const int lane = tid & 63;
    const int wid  = tid >> 6;          // 0..3 (4 waves)

    __shared__ int    s_wtot[4];
    __shared__ double s_red[8];

    const float4* __restrict__ in4 = (const float4*)pitch;

    double sum = 0.0, sumsq = 0.0;
    long long count_so_far = 0;

    // bits for lanes strictly above mine (within my wave)
    const unsigned long long above =
        (lane == 63) ? 0ULL : (~0ULL << (lane + 1));

    const long long nchunks = (n + 2047) >> 11;   // 2048-element chunks
    for (long long c = nchunks - 1; c >= 0; --c) {
        const long long base = (c << 11) + (long long)tid * 8;
        float v[8];
        if (base + 8 <= n) {
            // base is a multiple of 8 -> float4-aligned
            const float4 x = in4[(base >> 2)];
            const float4 y = in4[(base >> 2) + 1];
            v[0] = x.x; v[1] = x.y; v[2] = x.z; v[3] = x.w;
            v[4] = y.x; v[5] = y.y; v[6] = y.z; v[7] = y.w;
        } else {
#pragma unroll
            for (int j = 0; j < 8; ++j) {
                const long long idx = base + j;
                v[j] = (idx < n) ? pitch[idx] : 0.0f;
            }
        }

        int valid[8];
        int suff_wave = 0;   // valid elems in higher lanes of my wave
        int wtot = 0;        // valid elems in my wave (wave-uniform)
#pragma unroll
        for (int j = 0; j < 8; ++j) {
            valid[j] = (v[j] > 0.0f) ? 1 : 0;
            const unsigned long long m = __ballot(valid[j]);
            suff_wave += __popcll(m & above);
            wtot      += __popcll(m);
        }
        if (lane == 0) s_wtot[wid] = wtot;
        __syncthreads();
        int suff_after = suff_wave;      // + valid elems in higher waves
        int total = 0;
#pragma unroll
        for (int w = 0; w < 4; ++w) {
            const int t = s_wtot[w];
            total += t;
            if (w > wid) suff_after += t;
        }

        // Walk my 8 elements newest-to-oldest, assigning global reverse ranks.
        int r = 0;
#pragma unroll
        for (int j = 7; j >= 0; --j) {
            if (valid[j]) {
                const long long rev = count_so_far + suff_after + r;
                if (rev < BUF_SIZE) {
                    const double lp = (double)__log2f(v[j]);
                    sum   += lp;
                    sumsq += lp * lp;
                }
                r++;
            }
        }
        count_so_far += total;
        __syncthreads();                 // s_wtot reused next iteration
        if (count_so_far >= BUF_SIZE) break;   // uniform across block
    }

    // Wave-level double reduction, then 4-way LDS combine.
#pragma unroll
    for (int off = 32; off > 0; off >>= 1) {
        sum   += __shfl_down(sum,   off, 64);
        sumsq += __shfl_down(sumsq, off, 64);
    }
    if (lane == 0) { s_red[wid] = sum; s_red[4 + wid] = sumsq; }
    __syncthreads();
    if (tid == 0) {
        const double tsum   = s_red[0] + s_red[1] + s_red[2] + s_red[3];
        const double tsumsq = s_red[4] + s_red[5] + s_red[6] + s_red[7];
        const long long count =
            (count_so_far < BUF_SIZE) ? count_so_far : BUF_SIZE;
        float mean, stdv;
        if (count == 0) {
            mean = 0.0f;
            stdv = 1.0f;
        } else {
            mean = (float)(tsum / (double)count);
            if (count > 1) {
                double var = (tsumsq - tsum * tsum / (double)count) /
                             (double)(count - 1);
                if (var < 0.0) var = 0.0;
                stdv = (float)sqrt(var);
            } else {
                stdv = 1.0f;
            }
        }
        if (stdv < 1e-7f) stdv = 1e-7f;
        const float scale = TARGET_LOG_STD / stdv;
        stats[0] = scale;
        stats[1] = TARGET_LOG_MEAN - mean * scale;
    }
}

// Kernel 2: streaming elementwise transform — round-0/6 structure (one-shot
// blocks, 1 float4/thread — empirically the fastest streaming mode), with
// the store made nontemporal.
__global__ void apply_kernel(const float4* __restrict__ in4,
                             float4* __restrict__ out4, long long n4,
                             const float* __restrict__ pitch,
                             float* __restrict__ out, long long n,
                             const float* __restrict__ stats) {
    const float scale = stats[0];
    const float bias = stats[1];
    const long long gid = (long long)blockIdx.x * blockDim.x + threadIdx.x;
    const long long stride = (long long)gridDim.x * blockDim.x;

    for (long long k = gid; k < n4; k += stride) {
        const float4 p = in4[k];
        float4 o;
        o.x = (p.x > 0.0f) ? exp2f(fmaf(__log2f(p.x), scale, bias)) : 0.0f;
        o.y = (p.y > 0.0f) ? exp2f(fmaf(__log2f(p.y), scale, bias)) : 0.0f;
        o.z = (p.z > 0.0f) ? exp2f(fmaf(__log2f(p.z), scale, bias)) : 0.0f;
        o.w = (p.w > 0.0f) ? exp2f(fmaf(__log2f(p.w), scale, bias)) : 0.0f;
        nt_store_f4(out4 + k, o);
    }

    // Scalar tail (n not divisible by 4; dead for n = 2^25).
    const long long tail_start = n4 * 4;
    for (long long k = tail_start + gid; k < n; k += stride) {
        const float p = pitch[k];
        out[k] = (p > 0.0f) ? exp2f(fmaf(__log2f(p), scale, bias)) : 0.0f;
    }
}

extern "C" void kernel_launch(void* const* d_in, const int* in_sizes, int n_in,
                              void* d_out, int out_size, void* d_ws, size_t ws_size,
                              hipStream_t stream) {
    const float* pitch = (const float*)d_in[0];
    float* out = (float*)d_out;
    const long long n = (long long)in_sizes[0];
    float* stats = (float*)d_ws;   // [0]=scale, [1]=bias

    stats_kernel<<<1, 256, 0, stream>>>(pitch, n, stats);

    const long long n4 = n / 4;
    int blocks = (int)((n4 + 255) / 256);
    if (blocks > 32768) blocks = 32768;   // grid-stride covers the rest
    if (blocks < 1) blocks = 1;
    apply_kernel<<<blocks, 256, 0, stream>>>((const float4*)pitch, (float4*)out,
                                             n4, pitch, out, n, stats);
}